// Round 3
// baseline (6494.436 us; speedup 1.0000x reference)
//
#include <hip/hip_runtime.h>
#include <hip/hip_bf16.h>
#include <math.h>
#include <stdint.h>

#define HID 512
#define NB  512
#define TT  128
#define HOR 24
#define G4  2048
#define SLOT (512*512)
#define RING 4

typedef __attribute__((ext_vector_type(8))) short bf16x8;
typedef __attribute__((ext_vector_type(4))) float f32x4;

struct PK {
  const float* x;
  const __hip_bfloat16 *W0r, *W1c, *Wd0c, *Wd1c;
  const float *b0r, *b1r, *bd0s0, *bd0r, *bd1r, *Wx0r;
  const float *fcW, *fcb;
  __hip_bfloat16 *h0ring, *h1ring, *dh1, *dh2;   // dh1/dh2: 2-slot rings
  const __hip_bfloat16* zbuf;
  float *c0, *c1;
  int *f0, *f1, *fd1, *fd2;
  float* out;
};

__device__ __forceinline__ void gl_lds16(void* lds, const void* g) {
  __builtin_amdgcn_global_load_lds((const __attribute__((address_space(1))) void*)g,
                                   (__attribute__((address_space(3))) void*)lds, 16, 0, 0);
}

__device__ __forceinline__ float sigm(float x) { return 1.0f / (1.0f + expf(-x)); }

// ---- dataflow flag protocol (device-scope release/acquire) ----
__device__ __forceinline__ void waitflag(int* f) {
  if (threadIdx.x == 0) {
    while (__hip_atomic_load(f, __ATOMIC_RELAXED, __HIP_MEMORY_SCOPE_AGENT) < 32)
      __builtin_amdgcn_s_sleep(2);
    __builtin_amdgcn_fence(__ATOMIC_ACQUIRE, "agent");
  }
  __syncthreads();
}

__device__ __forceinline__ void arrive(int* f) {
  __syncthreads();   // s_waitcnt vmcnt(0) before s_barrier: stores drained
  if (threadIdx.x == 0) {
    __builtin_amdgcn_fence(__ATOMIC_RELEASE, "agent");
    __hip_atomic_fetch_add(f, 1, __ATOMIC_RELAXED, __HIP_MEMORY_SCOPE_AGENT);
  }
}

// ---- fused LSTM cell: 64x64 gate tile GEMM + epilogue (R1-verified core) ----
// smem: sA0@0(8K) sB0@8K sA1@16K sB1@24K gbuf@32K (64x68 f32)
__device__ void cell_gemm(const __hip_bfloat16* __restrict__ A1,
                          const __hip_bfloat16* __restrict__ A2,
                          const __hip_bfloat16* __restrict__ W, int Kt,
                          const float* __restrict__ bias,
                          const float* __restrict__ Wx, const float* __restrict__ xv, long xstride,
                          float* __restrict__ cst, __hip_bfloat16* __restrict__ hout,
                          int mt, int nt, char* smem) {
  const int tid = threadIdx.x;
  const int m0 = mt * 64, n0 = nt * 64;
  char* sAb[2] = {smem, smem + 16384};
  char* sBb[2] = {smem + 8192, smem + 24576};
  float* gbuf = (float*)(smem + 32768);

  const int lane = tid & 63, wv = tid >> 6;
  const int wm = (wv >> 1) * 32, wn = (wv & 1) * 32;
  const int mrow = lane & 15, quad = lane >> 4;

  f32x4 acc00 = {0.f,0.f,0.f,0.f}, acc01 = acc00, acc10 = acc00, acc11 = acc00;
  const int iters = Kt >> 6;

  auto stage = [&](int it) {
    const int k = it << 6;
    const __hip_bfloat16* As; int kl;
    if (k < 512) { As = A1; kl = k; } else { As = A2; kl = k - 512; }
    char* sA = sAb[it & 1]; char* sB = sBb[it & 1];
#pragma unroll
    for (int i = 0; i < 2; ++i) {
      int Gi = i * 256 + tid;
      int o = Gi >> 6, r = Gi & 63;
      gl_lds16(sA + (size_t)Gi * 16, As + (size_t)(m0 + r) * 512 + kl + o * 8);
      gl_lds16(sB + (size_t)Gi * 16, W + (size_t)(n0 + r) * Kt + k + o * 8);
    }
  };

  stage(0);
  for (int it = 0; it < iters; ++it) {
    __syncthreads();                      // buf[it] landed (vmcnt drain)
    if (it + 1 < iters) stage(it + 1);    // prefetch overlaps compute
    const char* sA = sAb[it & 1]; const char* sB = sBb[it & 1];
#pragma unroll
    for (int kh = 0; kh < 2; ++kh) {
      int ob = (kh << 2) + quad;
      bf16x8 a0 = *(bf16x8*)(sA + (size_t)((ob << 6) + wm + mrow) * 16);
      bf16x8 a1 = *(bf16x8*)(sA + (size_t)((ob << 6) + wm + 16 + mrow) * 16);
      bf16x8 b0 = *(bf16x8*)(sB + (size_t)((ob << 6) + wn + mrow) * 16);
      bf16x8 b1 = *(bf16x8*)(sB + (size_t)((ob << 6) + wn + 16 + mrow) * 16);
      acc00 = __builtin_amdgcn_mfma_f32_16x16x32_bf16(a0, b0, acc00, 0, 0, 0);
      acc01 = __builtin_amdgcn_mfma_f32_16x16x32_bf16(a0, b1, acc01, 0, 0, 0);
      acc10 = __builtin_amdgcn_mfma_f32_16x16x32_bf16(a1, b0, acc10, 0, 0, 0);
      acc11 = __builtin_amdgcn_mfma_f32_16x16x32_bf16(a1, b1, acc11, 0, 0, 0);
    }
  }

#pragma unroll
  for (int r = 0; r < 4; ++r) {
    gbuf[(size_t)(wm + quad * 4 + r) * 68 + wn + mrow]            = acc00[r];
    gbuf[(size_t)(wm + quad * 4 + r) * 68 + wn + 16 + mrow]       = acc01[r];
    gbuf[(size_t)(wm + 16 + quad * 4 + r) * 68 + wn + mrow]       = acc10[r];
    gbuf[(size_t)(wm + 16 + quad * 4 + r) * 68 + wn + 16 + mrow]  = acc11[r];
  }
  __syncthreads();

  const int jl = tid & 15;
  const int j0 = n0 >> 2;
#pragma unroll
  for (int ps = 0; ps < 4; ++ps) {
    int bl = (tid >> 4) + ps * 16;
    int b = m0 + bl;
    f32x4 gv = *(f32x4*)&gbuf[(size_t)bl * 68 + jl * 4];
    int n4 = n0 + jl * 4;
    f32x4 bz = *(const f32x4*)&bias[n4];
    float gi = gv[0] + bz[0], gf = gv[1] + bz[1], gg = gv[2] + bz[2], go = gv[3] + bz[3];
    if (Wx) {
      float x0 = xv[(size_t)b * xstride];
      float x1 = xv[(size_t)b * xstride + 1];
      f32x4 w01 = *(const f32x4*)&Wx[(size_t)n4 * 2];
      f32x4 w23 = *(const f32x4*)&Wx[(size_t)n4 * 2 + 4];
      gi += x0 * w01[0] + x1 * w01[1];
      gf += x0 * w01[2] + x1 * w01[3];
      gg += x0 * w23[0] + x1 * w23[1];
      go += x0 * w23[2] + x1 * w23[3];
    }
    float iv = sigm(gi), fv = sigm(gf), gvv = tanhf(gg), ov = sigm(go);
    size_t idx = (size_t)b * 512 + (j0 + jl);
    float cv = fv * cst[idx] + iv * gvv;
    cst[idx] = cv;
    hout[idx] = __float2bfloat16(ov * tanhf(cv));
  }
}

// off-critical-path output GEMV: pred[b,:] = dh2[b,:] @ fcW^T + fcb
__device__ void pred_job(const __hip_bfloat16* h2, const float* fcW, const float* fcb,
                         float* outp, int d2, int mt) {
  const int wv = threadIdx.x >> 6, lane = threadIdx.x & 63;
  for (int i = 0; i < 16; ++i) {
    int b = mt * 64 + wv * 16 + i;
    float s0 = 0.f, s1 = 0.f;
    for (int k = lane; k < 512; k += 64) {
      float hv = __bfloat162float(h2[(size_t)b * 512 + k]);
      s0 += hv * fcW[k];
      s1 += hv * fcW[512 + k];
    }
    for (int off = 32; off; off >>= 1) {
      s0 += __shfl_down(s0, off);
      s1 += __shfl_down(s1, off);
    }
    if (lane == 0) {
      outp[(size_t)b * (HOR * 2) + d2 * 2]     = s0 + fcb[0];
      outp[(size_t)b * (HOR * 2) + d2 * 2 + 1] = s1 + fcb[1];
    }
  }
}

// Plain (non-cooperative) persistent kernel. Co-residency guaranteed:
// __launch_bounds__(256,2) caps VGPR<=256/wave; LDS 49KB*2 <= 160KB;
// 8 waves/CU <= 32 => 2 blocks/CU => all 512 blocks resident, no deadlock.
__global__ __launch_bounds__(256, 2) void seq2seq_persistent(PK p) {
  __shared__ __align__(16) char smem[50176];
  const int blk = blockIdx.x;

  if (blk < 256) {
    // role B: encoder layer1 (K=1024), then decoder cell2 (K=1024)
    const int t = blk, mt = t & 7, nt = t >> 3;
    for (int u = 0; u < TT; ++u) {
      waitflag(&p.f0[u * 8 + mt]);
      if (u >= 1) waitflag(&p.f1[(u - 1) * 8 + mt]);
      const __hip_bfloat16* A1 = p.h0ring + (size_t)(u & (RING - 1)) * SLOT;
      const __hip_bfloat16* A2 = (u == 0) ? p.zbuf
                                          : p.h1ring + (size_t)((u - 1) & (RING - 1)) * SLOT;
      cell_gemm(A1, A2, p.W1c, 1024, p.b1r, nullptr, nullptr, 0,
                p.c1, p.h1ring + (size_t)(u & (RING - 1)) * SLOT, mt, nt, smem);
      arrive(&p.f1[u * 8 + mt]);
    }
    for (int d = 0; d < HOR; ++d) {
      waitflag(&p.fd1[d * 8 + mt]);
      if (d == 0) waitflag(&p.f1[127 * 8 + mt]);
      else        waitflag(&p.fd2[(d - 1) * 8 + mt]);
      const __hip_bfloat16* A1 = p.dh1 + (size_t)(d & 1) * SLOT;
      const __hip_bfloat16* A2 = (d == 0) ? p.h1ring + (size_t)((TT - 1) & (RING - 1)) * SLOT
                                          : p.dh2 + (size_t)((d - 1) & 1) * SLOT;
      cell_gemm(A1, A2, p.Wd1c, 1024, p.bd1r, nullptr, nullptr, 0,
                p.c1, p.dh2 + (size_t)(d & 1) * SLOT, mt, nt, smem);
      arrive(&p.fd2[d * 8 + mt]);
    }
  } else {
    // role A: encoder layer0 (K=512), then decoder cell1 (K=1024, pred folded) + preds
    const int t = blk - 256, mt = t & 7, nt = t >> 3;
    for (int s = 0; s < TT; ++s) {
      if (s >= 1) waitflag(&p.f0[(s - 1) * 8 + mt]);
      if (s >= RING) waitflag(&p.f1[(s - RING) * 8 + mt]);   // ring WAR gate
      const __hip_bfloat16* A1 = (s == 0) ? p.zbuf
                                          : p.h0ring + (size_t)((s - 1) & (RING - 1)) * SLOT;
      cell_gemm(A1, nullptr, p.W0r, 512, p.b0r, p.Wx0r, p.x + (size_t)s * 2, 256,
                p.c0, p.h0ring + (size_t)(s & (RING - 1)) * SLOT, mt, nt, smem);
      arrive(&p.f0[s * 8 + mt]);
    }
    for (int d = 0; d < HOR; ++d) {
      const __hip_bfloat16 *A1, *A2; const float* bias;
      if (d == 0) {
        waitflag(&p.f0[127 * 8 + mt]);
        A1 = p.h0ring + (size_t)((TT - 1) & (RING - 1)) * SLOT; A2 = p.zbuf; bias = p.bd0s0;
      } else {
        waitflag(&p.fd1[(d - 1) * 8 + mt]);
        waitflag(&p.fd2[(d - 1) * 8 + mt]);
        A1 = p.dh1 + (size_t)((d - 1) & 1) * SLOT;
        A2 = p.dh2 + (size_t)((d - 1) & 1) * SLOT;
        bias = p.bd0r;
      }
      cell_gemm(A1, A2, p.Wd0c, 1024, bias, nullptr, nullptr, 0,
                p.c0, p.dh1 + (size_t)(d & 1) * SLOT, mt, nt, smem);
      arrive(&p.fd1[d * 8 + mt]);
      if (nt == 0 && d >= 1)
        pred_job(p.dh2 + (size_t)((d - 1) & 1) * SLOT, p.fcW, p.fcb, p.out, d - 1, mt);
    }
    if (nt == 0) {
      waitflag(&p.fd2[23 * 8 + mt]);
      pred_job(p.dh2 + (size_t)(23 & 1) * SLOT, p.fcW, p.fcb, p.out, 23, mt);
    }
  }
}

// Build gate-interleaved bf16 weights, combined biases, and the pred-fold:
// Wd0c[:,512:1024] = dWih0 @ fcW  (rank-2 fold of decoder feedback)
__global__ void prep_weights(
    const float* eWih0, const float* eWhh0, const float* ebih0, const float* ebhh0,
    const float* eWih1, const float* eWhh1, const float* ebih1, const float* ebhh1,
    const float* dWih0, const float* dWhh0, const float* dbih0, const float* dbhh0,
    const float* dWih1, const float* dWhh1, const float* dbih1, const float* dbhh1,
    const float* fcW, const float* fcb,
    __hip_bfloat16* W0r, __hip_bfloat16* W1c, __hip_bfloat16* Wd0c, __hip_bfloat16* Wd1c,
    float* b0r, float* b1r, float* bd0s0, float* bd0r, float* bd1r, float* Wx0r) {
  long idx = (long)blockIdx.x * blockDim.x + threadIdx.x;
  if (idx >= (long)G4 * 3584) return;
  int np = (int)(idx / 3584), kk = (int)(idx % 3584);
  int g = np & 3, j = np >> 2;
  int srow = g * HID + j;
  if (kk < 512) {
    W0r[(size_t)np * 512 + kk] = __float2bfloat16(eWhh0[(size_t)srow * 512 + kk]);
  } else if (kk < 1536) {
    int k2 = kk - 512;
    float v = (k2 < 512) ? eWih1[(size_t)srow * 512 + k2] : eWhh1[(size_t)srow * 512 + (k2 - 512)];
    W1c[(size_t)np * 1024 + k2] = __float2bfloat16(v);
  } else if (kk < 2560) {
    int k2 = kk - 1536;
    float v;
    if (k2 < 512) v = dWhh0[(size_t)srow * 512 + k2];
    else {
      int k3 = k2 - 512;
      v = dWih0[srow * 2] * fcW[k3] + dWih0[srow * 2 + 1] * fcW[512 + k3];
    }
    Wd0c[(size_t)np * 1024 + k2] = __float2bfloat16(v);
  } else {
    int k2 = kk - 2560;
    float v = (k2 < 512) ? dWih1[(size_t)srow * 512 + k2] : dWhh1[(size_t)srow * 512 + (k2 - 512)];
    Wd1c[(size_t)np * 1024 + k2] = __float2bfloat16(v);
  }
  if (kk == 0) {
    b0r[np] = ebih0[srow] + ebhh0[srow];
    b1r[np] = ebih1[srow] + ebhh1[srow];
    float bs0 = dbih0[srow] + dbhh0[srow];
    bd0s0[np] = bs0;
    bd0r[np] = bs0 + dWih0[srow * 2] * fcb[0] + dWih0[srow * 2 + 1] * fcb[1];
    bd1r[np] = dbih1[srow] + dbhh1[srow];
    Wx0r[np * 2]     = eWih0[srow * 2];
    Wx0r[np * 2 + 1] = eWih0[srow * 2 + 1];
  }
}

extern "C" void kernel_launch(void* const* d_in, const int* in_sizes, int n_in,
                              void* d_out, int out_size, void* d_ws, size_t ws_size,
                              hipStream_t stream) {
  (void)in_sizes; (void)n_in; (void)out_size; (void)ws_size;
  const float* x     = (const float*)d_in[0];
  const float* eWih0 = (const float*)d_in[1];
  const float* eWhh0 = (const float*)d_in[2];
  const float* ebih0 = (const float*)d_in[3];
  const float* ebhh0 = (const float*)d_in[4];
  const float* eWih1 = (const float*)d_in[5];
  const float* eWhh1 = (const float*)d_in[6];
  const float* ebih1 = (const float*)d_in[7];
  const float* ebhh1 = (const float*)d_in[8];
  const float* dWih0 = (const float*)d_in[9];
  const float* dWhh0 = (const float*)d_in[10];
  const float* dbih0 = (const float*)d_in[11];
  const float* dbhh0 = (const float*)d_in[12];
  const float* dWih1 = (const float*)d_in[13];
  const float* dWhh1 = (const float*)d_in[14];
  const float* dbih1 = (const float*)d_in[15];
  const float* dbhh1 = (const float*)d_in[16];
  const float* fcW   = (const float*)d_in[17];
  const float* fcb   = (const float*)d_in[18];

  char* ws = (char*)d_ws;
  size_t off = 0;
  auto alloc = [&](size_t bytes) -> char* {
    char* pp = ws + off;
    off = (off + bytes + 255) & ~(size_t)255;
    return pp;
  };

  __hip_bfloat16* W0r  = (__hip_bfloat16*)alloc((size_t)G4 * 512 * 2);
  __hip_bfloat16* W1c  = (__hip_bfloat16*)alloc((size_t)G4 * 1024 * 2);
  __hip_bfloat16* Wd0c = (__hip_bfloat16*)alloc((size_t)G4 * 1024 * 2);
  __hip_bfloat16* Wd1c = (__hip_bfloat16*)alloc((size_t)G4 * 1024 * 2);
  float* b0r   = (float*)alloc(G4 * 4);
  float* b1r   = (float*)alloc(G4 * 4);
  float* bd0s0 = (float*)alloc(G4 * 4);
  float* bd0r  = (float*)alloc(G4 * 4);
  float* bd1r  = (float*)alloc(G4 * 4);
  float* Wx0r  = (float*)alloc(G4 * 2 * 4);

  __hip_bfloat16* h0ring = (__hip_bfloat16*)alloc((size_t)RING * SLOT * 2);
  __hip_bfloat16* h1ring = (__hip_bfloat16*)alloc((size_t)RING * SLOT * 2);
  __hip_bfloat16* dh1    = (__hip_bfloat16*)alloc((size_t)2 * SLOT * 2);
  __hip_bfloat16* dh2    = (__hip_bfloat16*)alloc((size_t)2 * SLOT * 2);

  char* zbase = ws + off;
  __hip_bfloat16* zbuf = (__hip_bfloat16*)alloc((size_t)SLOT * 2);
  float* c0 = (float*)alloc((size_t)SLOT * 4);
  float* c1 = (float*)alloc((size_t)SLOT * 4);
  int* f0  = (int*)alloc(TT * 8 * 4);
  int* f1  = (int*)alloc(TT * 8 * 4);
  int* fd1 = (int*)alloc(HOR * 8 * 4);
  int* fd2 = (int*)alloc(HOR * 8 * 4);
  size_t zbytes = (size_t)((ws + off) - zbase);

  hipMemsetAsync(zbase, 0, zbytes, stream);
  prep_weights<<<(int)(((long)G4 * 3584 + 255) / 256), 256, 0, stream>>>(
      eWih0, eWhh0, ebih0, ebhh0, eWih1, eWhh1, ebih1, ebhh1,
      dWih0, dWhh0, dbih0, dbhh0, dWih1, dWhh1, dbih1, dbhh1,
      fcW, fcb, W0r, W1c, Wd0c, Wd1c, b0r, b1r, bd0s0, bd0r, bd1r, Wx0r);

  PK p;
  p.x = x;
  p.W0r = W0r; p.W1c = W1c; p.Wd0c = Wd0c; p.Wd1c = Wd1c;
  p.b0r = b0r; p.b1r = b1r; p.bd0s0 = bd0s0; p.bd0r = bd0r; p.bd1r = bd1r; p.Wx0r = Wx0r;
  p.fcW = fcW; p.fcb = fcb;
  p.h0ring = h0ring; p.h1ring = h1ring; p.dh1 = dh1; p.dh2 = dh2;
  p.zbuf = zbuf; p.c0 = c0; p.c1 = c1;
  p.f0 = f0; p.f1 = f1; p.fd1 = fd1; p.fd2 = fd2;
  p.out = (float*)d_out;

  seq2seq_persistent<<<512, 256, 0, stream>>>(p);
}

// Round 4
// 4166.933 us; speedup vs baseline: 1.5586x; 1.5586x over previous
//
#include <hip/hip_runtime.h>
#include <hip/hip_bf16.h>
#include <math.h>
#include <stdint.h>

#define HID 512
#define NB  512
#define TT  128
#define HOR 24
#define G4  2048
#define SLOT (512*512)

typedef __attribute__((ext_vector_type(8))) short bf16x8;
typedef __attribute__((ext_vector_type(4))) float f32x4;

struct PK {
  const float* x;
  const __hip_bfloat16 *W0r, *W1c, *Wd0c, *Wd1c;
  const float *b0r, *b1r, *bd0s0, *bd0r, *bd1r, *Wx0r;
  const float *fcW, *fcb;
  __hip_bfloat16 *h0buf, *h1buf, *dh1buf, *dh2buf;  // unique buffer per step
  const __hip_bfloat16* zbuf;
  float *c0, *c1;
  int *f0, *f1, *fd1, *fd2;
  float* out;
};

__device__ __forceinline__ void gl_lds16(void* lds, const void* g) {
  __builtin_amdgcn_global_load_lds((const __attribute__((address_space(1))) void*)g,
                                   (__attribute__((address_space(3))) void*)lds, 16, 0, 0);
}

__device__ __forceinline__ float sigm(float x) { return 1.0f / (1.0f + expf(-x)); }

// ---- fence-free dataflow flags ----
// Producers push h-state to the device-coherent point (system-scope stores),
// then bump the flag (agent atomic, same coherent point). Consumers spin on
// the flag, then read addresses they have NEVER read before -> no stale
// cache line can exist; first read pulls fresh data. No cache invalidation.
__device__ __forceinline__ void waitflag(int* f) {
  if (threadIdx.x == 0) {
    while (__hip_atomic_load(f, __ATOMIC_RELAXED, __HIP_MEMORY_SCOPE_AGENT) < 32)
      __builtin_amdgcn_s_sleep(2);
  }
  __syncthreads();
}

__device__ __forceinline__ void arrive(int* f) {
  __syncthreads();   // s_waitcnt vmcnt(0) before s_barrier: h-stores acked at LLC
  if (threadIdx.x == 0)
    __hip_atomic_fetch_add(f, 1, __ATOMIC_RELAXED, __HIP_MEMORY_SCOPE_AGENT);
}

// ---- fused LSTM cell: 64x64 gate tile GEMM + epilogue ----
// smem: sA0@0(8K) sB0@8K sA1@16K sB1@24K gbuf@32K (64x68 f32)
__device__ void cell_gemm(const __hip_bfloat16* __restrict__ A1,
                          const __hip_bfloat16* __restrict__ A2,
                          const __hip_bfloat16* __restrict__ W, int Kt,
                          const float* __restrict__ bias,
                          const float* __restrict__ Wx, const float* __restrict__ xv, long xstride,
                          float* __restrict__ cst, __hip_bfloat16* __restrict__ hout,
                          int mt, int nt, char* smem) {
  const int tid = threadIdx.x;
  const int m0 = mt * 64, n0 = nt * 64;
  char* sAb[2] = {smem, smem + 16384};
  char* sBb[2] = {smem + 8192, smem + 24576};
  float* gbuf = (float*)(smem + 32768);

  const int lane = tid & 63, wv = tid >> 6;
  const int wm = (wv >> 1) * 32, wn = (wv & 1) * 32;
  const int mrow = lane & 15, quad = lane >> 4;

  f32x4 acc00 = {0.f,0.f,0.f,0.f}, acc01 = acc00, acc10 = acc00, acc11 = acc00;
  const int iters = Kt >> 6;

  auto stage = [&](int it) {
    const int k = it << 6;
    const __hip_bfloat16* As; int kl;
    if (k < 512) { As = A1; kl = k; } else { As = A2; kl = k - 512; }
    char* sA = sAb[it & 1]; char* sB = sBb[it & 1];
#pragma unroll
    for (int i = 0; i < 2; ++i) {
      int Gi = i * 256 + tid;
      int o = Gi >> 6, r = Gi & 63;
      gl_lds16(sA + (size_t)Gi * 16, As + (size_t)(m0 + r) * 512 + kl + o * 8);
      gl_lds16(sB + (size_t)Gi * 16, W + (size_t)(n0 + r) * Kt + k + o * 8);
    }
  };

  stage(0);
  for (int it = 0; it < iters; ++it) {
    __syncthreads();                      // buf[it] landed (vmcnt drain)
    if (it + 1 < iters) stage(it + 1);    // staging overlaps compute below
    const char* sA = sAb[it & 1]; const char* sB = sBb[it & 1];
#pragma unroll
    for (int kh = 0; kh < 2; ++kh) {
      int ob = (kh << 2) + quad;
      bf16x8 a0 = *(bf16x8*)(sA + (size_t)((ob << 6) + wm + mrow) * 16);
      bf16x8 a1 = *(bf16x8*)(sA + (size_t)((ob << 6) + wm + 16 + mrow) * 16);
      bf16x8 b0 = *(bf16x8*)(sB + (size_t)((ob << 6) + wn + mrow) * 16);
      bf16x8 b1 = *(bf16x8*)(sB + (size_t)((ob << 6) + wn + 16 + mrow) * 16);
      acc00 = __builtin_amdgcn_mfma_f32_16x16x32_bf16(a0, b0, acc00, 0, 0, 0);
      acc01 = __builtin_amdgcn_mfma_f32_16x16x32_bf16(a0, b1, acc01, 0, 0, 0);
      acc10 = __builtin_amdgcn_mfma_f32_16x16x32_bf16(a1, b0, acc10, 0, 0, 0);
      acc11 = __builtin_amdgcn_mfma_f32_16x16x32_bf16(a1, b1, acc11, 0, 0, 0);
    }
  }

#pragma unroll
  for (int r = 0; r < 4; ++r) {
    gbuf[(size_t)(wm + quad * 4 + r) * 68 + wn + mrow]            = acc00[r];
    gbuf[(size_t)(wm + quad * 4 + r) * 68 + wn + 16 + mrow]       = acc01[r];
    gbuf[(size_t)(wm + 16 + quad * 4 + r) * 68 + wn + mrow]       = acc10[r];
    gbuf[(size_t)(wm + 16 + quad * 4 + r) * 68 + wn + 16 + mrow]  = acc11[r];
  }
  __syncthreads();

  const int jl = tid & 15;
  const int j0 = n0 >> 2;
#pragma unroll
  for (int ps = 0; ps < 4; ++ps) {
    int bl = (tid >> 4) + ps * 16;
    int b = m0 + bl;
    f32x4 gv = *(f32x4*)&gbuf[(size_t)bl * 68 + jl * 4];
    int n4 = n0 + jl * 4;
    f32x4 bz = *(const f32x4*)&bias[n4];
    float gi = gv[0] + bz[0], gf = gv[1] + bz[1], gg = gv[2] + bz[2], go = gv[3] + bz[3];
    if (Wx) {
      float x0 = xv[(size_t)b * xstride];
      float x1 = xv[(size_t)b * xstride + 1];
      f32x4 w01 = *(const f32x4*)&Wx[(size_t)n4 * 2];
      f32x4 w23 = *(const f32x4*)&Wx[(size_t)n4 * 2 + 4];
      gi += x0 * w01[0] + x1 * w01[1];
      gf += x0 * w01[2] + x1 * w01[3];
      gg += x0 * w23[0] + x1 * w23[1];
      go += x0 * w23[2] + x1 * w23[3];
    }
    float iv = sigm(gi), fv = sigm(gf), gvv = tanhf(gg), ov = sigm(go);
    size_t idx = (size_t)b * 512 + (j0 + jl);
    float cv = fv * cst[idx] + iv * gvv;   // c tile is block-private: plain ld/st
    cst[idx] = cv;
    __hip_bfloat16 hv = __float2bfloat16(ov * tanhf(cv));
    // push h through to the device-coherent point (sc0|sc1, no-allocate)
    __hip_atomic_store((unsigned short*)&hout[idx],
                       __builtin_bit_cast(unsigned short, hv),
                       __ATOMIC_RELAXED, __HIP_MEMORY_SCOPE_SYSTEM);
  }
}

// output GEMV: pred[b,:] = dh2[b,:] @ fcW^T + fcb   (flag-gated, fresh addresses)
__device__ void pred_job(const __hip_bfloat16* h2, const float* fcW, const float* fcb,
                         float* outp, int d2, int mt) {
  const int wv = threadIdx.x >> 6, lane = threadIdx.x & 63;
  for (int i = 0; i < 16; ++i) {
    int b = mt * 64 + wv * 16 + i;
    float s0 = 0.f, s1 = 0.f;
    for (int k = lane; k < 512; k += 64) {
      float hv = __bfloat162float(h2[(size_t)b * 512 + k]);
      s0 += hv * fcW[k];
      s1 += hv * fcW[512 + k];
    }
    for (int off = 32; off; off >>= 1) {
      s0 += __shfl_down(s0, off);
      s1 += __shfl_down(s1, off);
    }
    if (lane == 0) {
      outp[(size_t)b * (HOR * 2) + d2 * 2]     = s0 + fcb[0];
      outp[(size_t)b * (HOR * 2) + d2 * 2 + 1] = s1 + fcb[1];
    }
  }
}

// Persistent kernel, 512 blocks, 2/CU guaranteed co-resident.
// blockIdx%8 < 4 -> layer0-role (XCDs 0-3 under round-robin heuristic: L2 holds
// only W0r/Wd0c); else layer1-role. Heuristic affects locality only, never
// correctness (coherence protocol is XCD-agnostic).
__global__ __launch_bounds__(256, 2) void seq2seq_persistent(PK p) {
  __shared__ __align__(16) char smem[50176];
  const int b7 = blockIdx.x & 7;
  const int q  = b7 & 3;
  const int r  = blockIdx.x >> 3;      // 0..63
  const int g  = (q << 1) | (r >> 5);  // batch group 0..7 (M-tile)
  const int nt = r & 31;               // gate tile 0..31
  const bool roleB = b7 >= 4;

  if (roleB) {
    // encoder layer1 (K=1024: [h0[u]; h1[u-1]]), then decoder cell2
    for (int u = 0; u < TT; ++u) {
      waitflag(&p.f0[u * 8 + g]);
      if (u >= 1) waitflag(&p.f1[(u - 1) * 8 + g]);
      const __hip_bfloat16* A1 = p.h0buf + (size_t)u * SLOT;
      const __hip_bfloat16* A2 = (u == 0) ? p.zbuf : p.h1buf + (size_t)(u - 1) * SLOT;
      cell_gemm(A1, A2, p.W1c, 1024, p.b1r, nullptr, nullptr, 0,
                p.c1, p.h1buf + (size_t)u * SLOT, g, nt, smem);
      arrive(&p.f1[u * 8 + g]);
    }
    for (int d = 0; d < HOR; ++d) {
      waitflag(&p.fd1[d * 8 + g]);
      if (d == 0) waitflag(&p.f1[127 * 8 + g]);
      else        waitflag(&p.fd2[(d - 1) * 8 + g]);
      const __hip_bfloat16* A1 = p.dh1buf + (size_t)d * SLOT;
      const __hip_bfloat16* A2 = (d == 0) ? p.h1buf + (size_t)127 * SLOT
                                          : p.dh2buf + (size_t)(d - 1) * SLOT;
      cell_gemm(A1, A2, p.Wd1c, 1024, p.bd1r, nullptr, nullptr, 0,
                p.c1, p.dh2buf + (size_t)d * SLOT, g, nt, smem);
      arrive(&p.fd2[d * 8 + g]);
    }
  } else {
    // encoder layer0 (K=512), then decoder cell1 (K=1024, pred folded) + preds
    for (int s = 0; s < TT; ++s) {
      if (s >= 1) waitflag(&p.f0[(s - 1) * 8 + g]);
      const __hip_bfloat16* A1 = (s == 0) ? p.zbuf : p.h0buf + (size_t)(s - 1) * SLOT;
      cell_gemm(A1, nullptr, p.W0r, 512, p.b0r, p.Wx0r, p.x + (size_t)s * 2, 256,
                p.c0, p.h0buf + (size_t)s * SLOT, g, nt, smem);
      arrive(&p.f0[s * 8 + g]);
    }
    for (int d = 0; d < HOR; ++d) {
      const __hip_bfloat16 *A1, *A2; const float* bias;
      if (d == 0) {
        waitflag(&p.f0[127 * 8 + g]);
        A1 = p.h0buf + (size_t)127 * SLOT; A2 = p.zbuf; bias = p.bd0s0;
      } else {
        waitflag(&p.fd1[(d - 1) * 8 + g]);
        waitflag(&p.fd2[(d - 1) * 8 + g]);
        A1 = p.dh1buf + (size_t)(d - 1) * SLOT;
        A2 = p.dh2buf + (size_t)(d - 1) * SLOT;
        bias = p.bd0r;
      }
      cell_gemm(A1, A2, p.Wd0c, 1024, bias, nullptr, nullptr, 0,
                p.c0, p.dh1buf + (size_t)d * SLOT, g, nt, smem);
      arrive(&p.fd1[d * 8 + g]);
      if (nt == 0 && d >= 1)
        pred_job(p.dh2buf + (size_t)(d - 1) * SLOT, p.fcW, p.fcb, p.out, d - 1, g);
    }
    if (nt == 0) {
      waitflag(&p.fd2[23 * 8 + g]);
      pred_job(p.dh2buf + (size_t)23 * SLOT, p.fcW, p.fcb, p.out, 23, g);
    }
  }
}

// Build gate-interleaved bf16 weights, combined biases, and the pred-fold:
// Wd0c[:,512:1024] = dWih0 @ fcW  (rank-2 fold of decoder feedback)
__global__ void prep_weights(
    const float* eWih0, const float* eWhh0, const float* ebih0, const float* ebhh0,
    const float* eWih1, const float* eWhh1, const float* ebih1, const float* ebhh1,
    const float* dWih0, const float* dWhh0, const float* dbih0, const float* dbhh0,
    const float* dWih1, const float* dWhh1, const float* dbih1, const float* dbhh1,
    const float* fcW, const float* fcb,
    __hip_bfloat16* W0r, __hip_bfloat16* W1c, __hip_bfloat16* Wd0c, __hip_bfloat16* Wd1c,
    float* b0r, float* b1r, float* bd0s0, float* bd0r, float* bd1r, float* Wx0r) {
  long idx = (long)blockIdx.x * blockDim.x + threadIdx.x;
  if (idx >= (long)G4 * 3584) return;
  int np = (int)(idx / 3584), kk = (int)(idx % 3584);
  int g = np & 3, j = np >> 2;
  int srow = g * HID + j;
  if (kk < 512) {
    W0r[(size_t)np * 512 + kk] = __float2bfloat16(eWhh0[(size_t)srow * 512 + kk]);
  } else if (kk < 1536) {
    int k2 = kk - 512;
    float v = (k2 < 512) ? eWih1[(size_t)srow * 512 + k2] : eWhh1[(size_t)srow * 512 + (k2 - 512)];
    W1c[(size_t)np * 1024 + k2] = __float2bfloat16(v);
  } else if (kk < 2560) {
    int k2 = kk - 1536;
    float v;
    if (k2 < 512) v = dWhh0[(size_t)srow * 512 + k2];
    else {
      int k3 = k2 - 512;
      v = dWih0[srow * 2] * fcW[k3] + dWih0[srow * 2 + 1] * fcW[512 + k3];
    }
    Wd0c[(size_t)np * 1024 + k2] = __float2bfloat16(v);
  } else {
    int k2 = kk - 2560;
    float v = (k2 < 512) ? dWih1[(size_t)srow * 512 + k2] : dWhh1[(size_t)srow * 512 + (k2 - 512)];
    Wd1c[(size_t)np * 1024 + k2] = __float2bfloat16(v);
  }
  if (kk == 0) {
    b0r[np] = ebih0[srow] + ebhh0[srow];
    b1r[np] = ebih1[srow] + ebhh1[srow];
    float bs0 = dbih0[srow] + dbhh0[srow];
    bd0s0[np] = bs0;
    bd0r[np] = bs0 + dWih0[srow * 2] * fcb[0] + dWih0[srow * 2 + 1] * fcb[1];
    bd1r[np] = dbih1[srow] + dbhh1[srow];
    Wx0r[np * 2]     = eWih0[srow * 2];
    Wx0r[np * 2 + 1] = eWih0[srow * 2 + 1];
  }
}

extern "C" void kernel_launch(void* const* d_in, const int* in_sizes, int n_in,
                              void* d_out, int out_size, void* d_ws, size_t ws_size,
                              hipStream_t stream) {
  (void)in_sizes; (void)n_in; (void)out_size; (void)ws_size;
  const float* x     = (const float*)d_in[0];
  const float* eWih0 = (const float*)d_in[1];
  const float* eWhh0 = (const float*)d_in[2];
  const float* ebih0 = (const float*)d_in[3];
  const float* ebhh0 = (const float*)d_in[4];
  const float* eWih1 = (const float*)d_in[5];
  const float* eWhh1 = (const float*)d_in[6];
  const float* ebih1 = (const float*)d_in[7];
  const float* ebhh1 = (const float*)d_in[8];
  const float* dWih0 = (const float*)d_in[9];
  const float* dWhh0 = (const float*)d_in[10];
  const float* dbih0 = (const float*)d_in[11];
  const float* dbhh0 = (const float*)d_in[12];
  const float* dWih1 = (const float*)d_in[13];
  const float* dWhh1 = (const float*)d_in[14];
  const float* dbih1 = (const float*)d_in[15];
  const float* dbhh1 = (const float*)d_in[16];
  const float* fcW   = (const float*)d_in[17];
  const float* fcb   = (const float*)d_in[18];

  char* ws = (char*)d_ws;
  size_t off = 0;
  auto alloc = [&](size_t bytes) -> char* {
    char* pp = ws + off;
    off = (off + bytes + 255) & ~(size_t)255;
    return pp;
  };

  __hip_bfloat16* W0r  = (__hip_bfloat16*)alloc((size_t)G4 * 512 * 2);
  __hip_bfloat16* W1c  = (__hip_bfloat16*)alloc((size_t)G4 * 1024 * 2);
  __hip_bfloat16* Wd0c = (__hip_bfloat16*)alloc((size_t)G4 * 1024 * 2);
  __hip_bfloat16* Wd1c = (__hip_bfloat16*)alloc((size_t)G4 * 1024 * 2);
  float* b0r   = (float*)alloc(G4 * 4);
  float* b1r   = (float*)alloc(G4 * 4);
  float* bd0s0 = (float*)alloc(G4 * 4);
  float* bd0r  = (float*)alloc(G4 * 4);
  float* bd1r  = (float*)alloc(G4 * 4);
  float* Wx0r  = (float*)alloc(G4 * 2 * 4);

  // per-step unique h buffers (~152 MB total; ws is >=256 MB per harness fill)
  __hip_bfloat16* h0buf  = (__hip_bfloat16*)alloc((size_t)TT * SLOT * 2);
  __hip_bfloat16* h1buf  = (__hip_bfloat16*)alloc((size_t)TT * SLOT * 2);
  __hip_bfloat16* dh1buf = (__hip_bfloat16*)alloc((size_t)HOR * SLOT * 2);
  __hip_bfloat16* dh2buf = (__hip_bfloat16*)alloc((size_t)HOR * SLOT * 2);

  char* zbase = ws + off;
  __hip_bfloat16* zbuf = (__hip_bfloat16*)alloc((size_t)SLOT * 2);
  float* c0 = (float*)alloc((size_t)SLOT * 4);
  float* c1 = (float*)alloc((size_t)SLOT * 4);
  int* f0  = (int*)alloc(TT * 8 * 4);
  int* f1  = (int*)alloc(TT * 8 * 4);
  int* fd1 = (int*)alloc(HOR * 8 * 4);
  int* fd2 = (int*)alloc(HOR * 8 * 4);
  size_t zbytes = (size_t)((ws + off) - zbase);

  hipMemsetAsync(zbase, 0, zbytes, stream);
  prep_weights<<<(int)(((long)G4 * 3584 + 255) / 256), 256, 0, stream>>>(
      eWih0, eWhh0, ebih0, ebhh0, eWih1, eWhh1, ebih1, ebhh1,
      dWih0, dWhh0, dbih0, dbhh0, dWih1, dWhh1, dbih1, dbhh1,
      fcW, fcb, W0r, W1c, Wd0c, Wd1c, b0r, b1r, bd0s0, bd0r, bd1r, Wx0r);

  PK p;
  p.x = x;
  p.W0r = W0r; p.W1c = W1c; p.Wd0c = Wd0c; p.Wd1c = Wd1c;
  p.b0r = b0r; p.b1r = b1r; p.bd0s0 = bd0s0; p.bd0r = bd0r; p.bd1r = bd1r; p.Wx0r = Wx0r;
  p.fcW = fcW; p.fcb = fcb;
  p.h0buf = h0buf; p.h1buf = h1buf; p.dh1buf = dh1buf; p.dh2buf = dh2buf;
  p.zbuf = zbuf; p.c0 = c0; p.c1 = c1;
  p.f0 = f0; p.f1 = f1; p.fd1 = fd1; p.fd2 = fd2;
  p.out = (float*)d_out;

  seq2seq_persistent<<<512, 256, 0, stream>>>(p);
}

// Round 5
// 2620.216 us; speedup vs baseline: 2.4786x; 1.5903x over previous
//
#include <hip/hip_runtime.h>
#include <hip/hip_bf16.h>
#include <math.h>
#include <stdint.h>

#define HID 512
#define NB  512
#define TT  128
#define HOR 24
#define G4  2048
#define SLOT (512*512)

typedef __attribute__((ext_vector_type(8))) short bf16x8;
typedef __attribute__((ext_vector_type(4))) float f32x4;

struct PK {
  const float* x;
  const __hip_bfloat16 *W0r, *W1c, *Wd0c, *Wd1c;
  const float *b0r, *b1r, *bd0s0, *bd0r, *bd1r, *Wx0r;
  const float *fcW, *fcb;
  __hip_bfloat16 *h0buf, *h1buf, *dh1buf, *dh2buf;  // unique buffer per step
  const __hip_bfloat16* zbuf;
  int *f0, *f1, *fd1, *fd2;
  float* out;
};

__device__ __forceinline__ void gl_lds16(void* lds, const void* g) {
  __builtin_amdgcn_global_load_lds((const __attribute__((address_space(1))) void*)g,
                                   (__attribute__((address_space(3))) void*)lds, 16, 0, 0);
}

__device__ __forceinline__ float sigm(float x) { return 1.0f / (1.0f + expf(-x)); }

// ---- fence-free dataflow flags (R4-proven): producers push h via system-scope
// stores (reach device-coherent point), flag bump agent-scope; consumers only
// ever read addresses they have never read -> no stale line can exist. ----
__device__ __forceinline__ void waitflag(int* f) {
  if (threadIdx.x == 0) {
    while (__hip_atomic_load(f, __ATOMIC_RELAXED, __HIP_MEMORY_SCOPE_AGENT) < 32)
      __builtin_amdgcn_s_sleep(2);
  }
  __syncthreads();
}

__device__ __forceinline__ void arrive(int* f) {
  __syncthreads();   // vmcnt(0) drain before s_barrier: h-stores are at LLC
  if (threadIdx.x == 0)
    __hip_atomic_fetch_add(f, 1, __ATOMIC_RELAXED, __HIP_MEMORY_SCOPE_AGENT);
}

// ---- register-resident weight fragments ----
// Wave owns gate-cols [nt*64 + wv*16, +16). B-frag for k-chunk kc:
// lane holds W[nrow = base + (lane&15)][kc*32 + (lane>>4)*8 .. +7].
template<int KC>
__device__ __forceinline__ void load_w(bf16x8* Breg, const __hip_bfloat16* W,
                                       int Kt, int nrow, int q) {
  const char* base = (const char*)W + ((size_t)nrow * Kt + q * 8) * 2;
#pragma unroll
  for (int kc = 0; kc < KC; ++kc)
    Breg[kc] = *(const bf16x8*)(base + (size_t)kc * 64);
}

// ---- one LSTM-cell GEMM step: A (64 x K) staged to LDS in K=128 chunks,
// double-buffered; W from registers. ITERS=4 (K=512) or 8 (K=1024, A1|A2). ----
template<int ITERS>
__device__ __forceinline__ void gemm_step(
    const __hip_bfloat16* __restrict__ A1,
    const __hip_bfloat16* __restrict__ A2,
    const bf16x8* __restrict__ Breg,
    int m0, char* __restrict__ smem, int lane, f32x4* __restrict__ acc) {
  const int s = lane & 15, q = lane >> 4;
  const int tid = threadIdx.x;
#pragma unroll
  for (int mi = 0; mi < 4; ++mi) acc[mi] = (f32x4){0.f, 0.f, 0.f, 0.f};

  auto stage = [&](int it) {
    const __hip_bfloat16* As = (ITERS == 4 || it < 4) ? A1 : A2;
    const int kloc = (ITERS == 4 ? it : (it & 3)) * 128;
    char* dst = smem + ((it & 1) ? 16384 : 0);
#pragma unroll
    for (int i = 0; i < 4; ++i) {
      const int u = i * 256 + tid;      // 0..1023 ; unit = octet*64 + row
      const int o = u >> 6, r = u & 63;
      gl_lds16(dst + (size_t)u * 16, As + (size_t)(m0 + r) * 512 + kloc + o * 8);
    }
  };
  stage(0);
#pragma unroll
  for (int it = 0; it < ITERS; ++it) {
    __syncthreads();                    // chunk[it] landed (vmcnt drain)
    if (it + 1 < ITERS) stage(it + 1);  // prefetch overlaps MFMA below
    const char* sA = smem + ((it & 1) ? 16384 : 0);
#pragma unroll
    for (int kl = 0; kl < 4; ++kl) {
#pragma unroll
      for (int mi = 0; mi < 4; ++mi) {
        bf16x8 a = *(const bf16x8*)(sA +
            (size_t)((((kl << 2) + q) << 6) + (mi << 4) + s) * 16);
        acc[mi] = __builtin_amdgcn_mfma_f32_16x16x32_bf16(
            a, Breg[(it << 2) + kl], acc[mi], 0, 0, 0);
      }
    }
  }
}

// ---- fused LSTM epilogue. Per-wave 4x16x20 f32 transpose buffer (wave-private,
// DS in-order, no block barrier). Lane ends owning 4 cells (one per mi):
// b = m0 + mi*16 + (lane>>2), h-col jg. c-state lives in creg across all steps. ----
__device__ __forceinline__ void epilogue(
    const f32x4* __restrict__ acc, float* __restrict__ tbuf,
    const f32x4 bz, const f32x4* w01, const f32x4* w23, const float2* xr,
    float* __restrict__ creg, __hip_bfloat16* __restrict__ hout,
    int m0, int jg, int lane) {
  const int s = lane & 15, q = lane >> 4;
  const int row_e = lane >> 2, jl = lane & 3;
#pragma unroll
  for (int mi = 0; mi < 4; ++mi) {
#pragma unroll
    for (int r = 0; r < 4; ++r)
      tbuf[mi * 320 + (q * 4 + r) * 20 + s] = acc[mi][r];
  }
#pragma unroll
  for (int mi = 0; mi < 4; ++mi) {
    f32x4 gv = *(const f32x4*)&tbuf[mi * 320 + row_e * 20 + jl * 4];
    float gi = gv[0] + bz[0], gf = gv[1] + bz[1];
    float gg = gv[2] + bz[2], go = gv[3] + bz[3];
    if (xr) {
      gi += xr[mi].x * (*w01)[0] + xr[mi].y * (*w01)[1];
      gf += xr[mi].x * (*w01)[2] + xr[mi].y * (*w01)[3];
      gg += xr[mi].x * (*w23)[0] + xr[mi].y * (*w23)[1];
      go += xr[mi].x * (*w23)[2] + xr[mi].y * (*w23)[3];
    }
    float iv = sigm(gi), fv = sigm(gf), gvv = tanhf(gg), ov = sigm(go);
    float cv = fv * creg[mi] + iv * gvv;
    creg[mi] = cv;
    __hip_bfloat16 hv = __float2bfloat16(ov * tanhf(cv));
    const int b = m0 + mi * 16 + row_e;
    __hip_atomic_store((unsigned short*)&hout[(size_t)b * 512 + jg],
                       __builtin_bit_cast(unsigned short, hv),
                       __ATOMIC_RELAXED, __HIP_MEMORY_SCOPE_SYSTEM);
  }
}

// output GEMV: pred[b,:] = dh2[b,:] @ fcW^T + fcb (flag-gated fresh addresses)
__device__ void pred_job(const __hip_bfloat16* h2, const float* fcW, const float* fcb,
                         float* outp, int d2, int mt) {
  const int wv = threadIdx.x >> 6, lane = threadIdx.x & 63;
  for (int i = 0; i < 16; ++i) {
    int b = mt * 64 + wv * 16 + i;
    float s0 = 0.f, s1 = 0.f;
    for (int k = lane; k < 512; k += 64) {
      float hv = __bfloat162float(h2[(size_t)b * 512 + k]);
      s0 += hv * fcW[k];
      s1 += hv * fcW[512 + k];
    }
    for (int off = 32; off; off >>= 1) {
      s0 += __shfl_down(s0, off);
      s1 += __shfl_down(s1, off);
    }
    if (lane == 0) {
      outp[(size_t)b * (HOR * 2) + d2 * 2]     = s0 + fcb[0];
      outp[(size_t)b * (HOR * 2) + d2 * 2 + 1] = s1 + fcb[1];
    }
  }
}

// Persistent kernel: 512 blocks, 2/CU by construction (LDS 52 KB, VGPR capped
// by __launch_bounds__(256,2)). g = blk&7 (batch group, pins g to one XCD under
// round-robin -> all h traffic for g is XCD-local); role alternates per CU pair.
__global__ __launch_bounds__(256, 2) void seq2seq_persistent(PK p) {
  __shared__ __align__(16) char smem[53248];   // 2x16KB A-staging + 4x5KB tbuf
  const int blk = blockIdx.x;
  const int g = blk & 7;
  const int role = (blk >> 3) & 1;
  const int nt = blk >> 4;                     // 0..31 gate-col tile
  const int m0 = g * 64;
  const int wv = threadIdx.x >> 6, lane = threadIdx.x & 63;
  const int s16 = lane & 15, q = lane >> 4;
  const int nrow = nt * 64 + wv * 16 + s16;    // B-frag gate-col row
  const int jl = lane & 3;
  const int jg = nt * 16 + wv * 4 + jl;        // h column this lane owns
  const int n4 = jg * 4;                       // gate base col (bias index)
  float* tbuf = (float*)(smem + 32768 + wv * 5120);

  f32x4 acc[4];
  bf16x8 Breg[32];                             // 128 VGPRs of weights
  float creg[4] = {0.f, 0.f, 0.f, 0.f};        // cell state, register-resident

  if (role == 1) {
    // ---- role B: encoder layer1 (K=1024: [h0[u]; h1[u-1]]), decoder cell2 ----
    load_w<32>(Breg, p.W1c, 1024, nrow, q);
    f32x4 bz = *(const f32x4*)&p.b1r[n4];
    for (int u = 0; u < TT; ++u) {
      waitflag(&p.f0[u * 8 + g]);
      if (u >= 1) waitflag(&p.f1[(u - 1) * 8 + g]);
      const __hip_bfloat16* A2 = (u == 0) ? p.zbuf : p.h1buf + (size_t)(u - 1) * SLOT;
      gemm_step<8>(p.h0buf + (size_t)u * SLOT, A2, Breg, m0, smem, lane, acc);
      epilogue(acc, tbuf, bz, nullptr, nullptr, nullptr, creg,
               p.h1buf + (size_t)u * SLOT, m0, jg, lane);
      arrive(&p.f1[u * 8 + g]);
    }
    load_w<32>(Breg, p.Wd1c, 1024, nrow, q);
    bz = *(const f32x4*)&p.bd1r[n4];
    for (int d = 0; d < HOR; ++d) {
      waitflag(&p.fd1[d * 8 + g]);
      const __hip_bfloat16* A2;
      if (d == 0) { waitflag(&p.f1[127 * 8 + g]); A2 = p.h1buf + (size_t)127 * SLOT; }
      else { waitflag(&p.fd2[(d - 1) * 8 + g]); A2 = p.dh2buf + (size_t)(d - 1) * SLOT; }
      gemm_step<8>(p.dh1buf + (size_t)d * SLOT, A2, Breg, m0, smem, lane, acc);
      epilogue(acc, tbuf, bz, nullptr, nullptr, nullptr, creg,
               p.dh2buf + (size_t)d * SLOT, m0, jg, lane);
      arrive(&p.fd2[d * 8 + g]);
    }
  } else {
    // ---- role A: encoder layer0 (K=512), decoder cell1 (K=1024, pred folded) ----
    load_w<16>(Breg, p.W0r, 512, nrow, q);
    f32x4 bz = *(const f32x4*)&p.b0r[n4];
    f32x4 w01 = *(const f32x4*)&p.Wx0r[n4 * 2];
    f32x4 w23 = *(const f32x4*)&p.Wx0r[n4 * 2 + 4];
    const int row_e = lane >> 2;
    for (int s = 0; s < TT; ++s) {
      float2 xr[4];
#pragma unroll
      for (int mi = 0; mi < 4; ++mi)
        xr[mi] = *(const float2*)&p.x[((size_t)(m0 + mi * 16 + row_e) * TT + s) * 2];
      if (s >= 1) waitflag(&p.f0[(s - 1) * 8 + g]);
      gemm_step<4>((s == 0) ? p.zbuf : p.h0buf + (size_t)(s - 1) * SLOT, nullptr,
                   Breg, m0, smem, lane, acc);
      epilogue(acc, tbuf, bz, &w01, &w23, xr, creg,
               p.h0buf + (size_t)s * SLOT, m0, jg, lane);
      arrive(&p.f0[s * 8 + g]);
    }
    load_w<32>(Breg, p.Wd0c, 1024, nrow, q);
    f32x4 bzd0 = *(const f32x4*)&p.bd0s0[n4];
    f32x4 bzd  = *(const f32x4*)&p.bd0r[n4];
    for (int d = 0; d < HOR; ++d) {
      const __hip_bfloat16 *A1, *A2; f32x4 bzu;
      if (d == 0) {
        waitflag(&p.f0[127 * 8 + g]);
        A1 = p.h0buf + (size_t)127 * SLOT; A2 = p.zbuf; bzu = bzd0;
      } else {
        waitflag(&p.fd1[(d - 1) * 8 + g]);
        waitflag(&p.fd2[(d - 1) * 8 + g]);
        A1 = p.dh1buf + (size_t)(d - 1) * SLOT;
        A2 = p.dh2buf + (size_t)(d - 1) * SLOT;
        bzu = bzd;
      }
      gemm_step<8>(A1, A2, Breg, m0, smem, lane, acc);
      epilogue(acc, tbuf, bzu, nullptr, nullptr, nullptr, creg,
               p.dh1buf + (size_t)d * SLOT, m0, jg, lane);
      arrive(&p.fd1[d * 8 + g]);
      if (nt == 0 && d >= 1)
        pred_job(p.dh2buf + (size_t)(d - 1) * SLOT, p.fcW, p.fcb, p.out, d - 1, g);
    }
    if (nt == 0) {
      waitflag(&p.fd2[23 * 8 + g]);
      pred_job(p.dh2buf + (size_t)23 * SLOT, p.fcW, p.fcb, p.out, 23, g);
    }
  }
}

// Build gate-interleaved bf16 weights, combined biases, and the pred-fold:
// Wd0c[:,512:1024] = dWih0 @ fcW  (rank-2 fold of decoder feedback)
__global__ void prep_weights(
    const float* eWih0, const float* eWhh0, const float* ebih0, const float* ebhh0,
    const float* eWih1, const float* eWhh1, const float* ebih1, const float* ebhh1,
    const float* dWih0, const float* dWhh0, const float* dbih0, const float* dbhh0,
    const float* dWih1, const float* dWhh1, const float* dbih1, const float* dbhh1,
    const float* fcW, const float* fcb,
    __hip_bfloat16* W0r, __hip_bfloat16* W1c, __hip_bfloat16* Wd0c, __hip_bfloat16* Wd1c,
    float* b0r, float* b1r, float* bd0s0, float* bd0r, float* bd1r, float* Wx0r) {
  long idx = (long)blockIdx.x * blockDim.x + threadIdx.x;
  if (idx >= (long)G4 * 3584) return;
  int np = (int)(idx / 3584), kk = (int)(idx % 3584);
  int g = np & 3, j = np >> 2;
  int srow = g * HID + j;
  if (kk < 512) {
    W0r[(size_t)np * 512 + kk] = __float2bfloat16(eWhh0[(size_t)srow * 512 + kk]);
  } else if (kk < 1536) {
    int k2 = kk - 512;
    float v = (k2 < 512) ? eWih1[(size_t)srow * 512 + k2] : eWhh1[(size_t)srow * 512 + (k2 - 512)];
    W1c[(size_t)np * 1024 + k2] = __float2bfloat16(v);
  } else if (kk < 2560) {
    int k2 = kk - 1536;
    float v;
    if (k2 < 512) v = dWhh0[(size_t)srow * 512 + k2];
    else {
      int k3 = k2 - 512;
      v = dWih0[srow * 2] * fcW[k3] + dWih0[srow * 2 + 1] * fcW[512 + k3];
    }
    Wd0c[(size_t)np * 1024 + k2] = __float2bfloat16(v);
  } else {
    int k2 = kk - 2560;
    float v = (k2 < 512) ? dWih1[(size_t)srow * 512 + k2] : dWhh1[(size_t)srow * 512 + (k2 - 512)];
    Wd1c[(size_t)np * 1024 + k2] = __float2bfloat16(v);
  }
  if (kk == 0) {
    b0r[np] = ebih0[srow] + ebhh0[srow];
    b1r[np] = ebih1[srow] + ebhh1[srow];
    float bs0 = dbih0[srow] + dbhh0[srow];
    bd0s0[np] = bs0;
    bd0r[np] = bs0 + dWih0[srow * 2] * fcb[0] + dWih0[srow * 2 + 1] * fcb[1];
    bd1r[np] = dbih1[srow] + dbhh1[srow];
    Wx0r[np * 2]     = eWih0[srow * 2];
    Wx0r[np * 2 + 1] = eWih0[srow * 2 + 1];
  }
}

extern "C" void kernel_launch(void* const* d_in, const int* in_sizes, int n_in,
                              void* d_out, int out_size, void* d_ws, size_t ws_size,
                              hipStream_t stream) {
  (void)in_sizes; (void)n_in; (void)out_size; (void)ws_size;
  const float* x     = (const float*)d_in[0];
  const float* eWih0 = (const float*)d_in[1];
  const float* eWhh0 = (const float*)d_in[2];
  const float* ebih0 = (const float*)d_in[3];
  const float* ebhh0 = (const float*)d_in[4];
  const float* eWih1 = (const float*)d_in[5];
  const float* eWhh1 = (const float*)d_in[6];
  const float* ebih1 = (const float*)d_in[7];
  const float* ebhh1 = (const float*)d_in[8];
  const float* dWih0 = (const float*)d_in[9];
  const float* dWhh0 = (const float*)d_in[10];
  const float* dbih0 = (const float*)d_in[11];
  const float* dbhh0 = (const float*)d_in[12];
  const float* dWih1 = (const float*)d_in[13];
  const float* dWhh1 = (const float*)d_in[14];
  const float* dbih1 = (const float*)d_in[15];
  const float* dbhh1 = (const float*)d_in[16];
  const float* fcW   = (const float*)d_in[17];
  const float* fcb   = (const float*)d_in[18];

  char* ws = (char*)d_ws;
  size_t off = 0;
  auto alloc = [&](size_t bytes) -> char* {
    char* pp = ws + off;
    off = (off + bytes + 255) & ~(size_t)255;
    return pp;
  };

  __hip_bfloat16* W0r  = (__hip_bfloat16*)alloc((size_t)G4 * 512 * 2);
  __hip_bfloat16* W1c  = (__hip_bfloat16*)alloc((size_t)G4 * 1024 * 2);
  __hip_bfloat16* Wd0c = (__hip_bfloat16*)alloc((size_t)G4 * 1024 * 2);
  __hip_bfloat16* Wd1c = (__hip_bfloat16*)alloc((size_t)G4 * 1024 * 2);
  float* b0r   = (float*)alloc(G4 * 4);
  float* b1r   = (float*)alloc(G4 * 4);
  float* bd0s0 = (float*)alloc(G4 * 4);
  float* bd0r  = (float*)alloc(G4 * 4);
  float* bd1r  = (float*)alloc(G4 * 4);
  float* Wx0r  = (float*)alloc(G4 * 2 * 4);

  __hip_bfloat16* h0buf  = (__hip_bfloat16*)alloc((size_t)TT * SLOT * 2);
  __hip_bfloat16* h1buf  = (__hip_bfloat16*)alloc((size_t)TT * SLOT * 2);
  __hip_bfloat16* dh1buf = (__hip_bfloat16*)alloc((size_t)HOR * SLOT * 2);
  __hip_bfloat16* dh2buf = (__hip_bfloat16*)alloc((size_t)HOR * SLOT * 2);

  char* zbase = ws + off;
  __hip_bfloat16* zbuf = (__hip_bfloat16*)alloc((size_t)SLOT * 2);
  int* f0  = (int*)alloc(TT * 8 * 4);
  int* f1  = (int*)alloc(TT * 8 * 4);
  int* fd1 = (int*)alloc(HOR * 8 * 4);
  int* fd2 = (int*)alloc(HOR * 8 * 4);
  size_t zbytes = (size_t)((ws + off) - zbase);

  hipMemsetAsync(zbase, 0, zbytes, stream);
  prep_weights<<<(int)(((long)G4 * 3584 + 255) / 256), 256, 0, stream>>>(
      eWih0, eWhh0, ebih0, ebhh0, eWih1, eWhh1, ebih1, ebhh1,
      dWih0, dWhh0, dbih0, dbhh0, dWih1, dWhh1, dbih1, dbhh1,
      fcW, fcb, W0r, W1c, Wd0c, Wd1c, b0r, b1r, bd0s0, bd0r, bd1r, Wx0r);

  PK p;
  p.x = x;
  p.W0r = W0r; p.W1c = W1c; p.Wd0c = Wd0c; p.Wd1c = Wd1c;
  p.b0r = b0r; p.b1r = b1r; p.bd0s0 = bd0s0; p.bd0r = bd0r; p.bd1r = bd1r; p.Wx0r = Wx0r;
  p.fcW = fcW; p.fcb = fcb;
  p.h0buf = h0buf; p.h1buf = h1buf; p.dh1buf = dh1buf; p.dh2buf = dh2buf;
  p.zbuf = zbuf;
  p.f0 = f0; p.f1 = f1; p.fd1 = fd1; p.fd2 = fd2;
  p.out = (float*)d_out;

  seq2seq_persistent<<<512, 256, 0, stream>>>(p);
}

// Round 8
// 1947.094 us; speedup vs baseline: 3.3355x; 1.3457x over previous
//
#include <hip/hip_runtime.h>
#include <hip/hip_bf16.h>
#include <math.h>
#include <stdint.h>

#define HID 512
#define NB  512
#define TT  128
#define HOR 24
#define G4  2048
#define SLOT (512*512)

typedef __attribute__((ext_vector_type(8))) short bf16x8;
typedef __attribute__((ext_vector_type(4))) float f32x4;

// flags padded to one 64B line each
#define FL(a, s, gg) ((a) + (((s) * 8 + (gg)) << 4))

struct PK {
  const float* x;
  const __hip_bfloat16 *W0r, *W1c, *Wd0c, *Wd1c;
  const float *b0r, *b1r, *bd0s0, *bd0r, *bd1r, *Wx0r;
  const float *fcW, *fcb;
  __hip_bfloat16 *h0buf, *h1buf, *dh1buf, *dh2buf;  // unique buffer per step
  const __hip_bfloat16* zbuf;
  int *f0, *f1, *fd1, *fd2;
  float* out;
};

__device__ __forceinline__ void gl_lds16(void* lds, const void* g) {
  __builtin_amdgcn_global_load_lds((const __attribute__((address_space(1))) void*)g,
                                   (__attribute__((address_space(3))) void*)lds, 16, 0, 0);
}

__device__ __forceinline__ float sigm(float x) { return 1.0f / (1.0f + expf(-x)); }

// ---- fence-free dataflow flags (R4/R5-proven protocol) ----
// Non-draining wait: s_barrier as an asm block with "memory" clobber — a
// compiler fence so staging can't be hoisted above the flag spin; no hardware
// drain needed (consumers only read never-before-read addresses, producers
// pushed via system-scope stores before the flag bump).
__device__ __forceinline__ void waitflag_nb(int* f) {
  if (threadIdx.x == 0) {
    while (__hip_atomic_load(f, __ATOMIC_RELAXED, __HIP_MEMORY_SCOPE_AGENT) < 32)
      __builtin_amdgcn_s_sleep(1);
  }
  asm volatile("s_barrier" ::: "memory");
}

__device__ __forceinline__ void arrive(int* f) {
  __syncthreads();   // vmcnt(0) drain: h-stores acked at coherent point
  if (threadIdx.x == 0)
    __hip_atomic_fetch_add(f, 1, __ATOMIC_RELAXED, __HIP_MEMORY_SCOPE_AGENT);
}

// ---- register-resident weight fragments (R5-proven layout) ----
template<int KC>
__device__ __forceinline__ void load_w(bf16x8* Breg, const __hip_bfloat16* W,
                                       int Kt, int nrow, int q) {
  const char* base = (const char*)W + ((size_t)nrow * Kt + q * 8) * 2;
#pragma unroll
  for (int kc = 0; kc < KC; ++kc)
    Breg[kc] = *(const bf16x8*)(base + (size_t)kc * 64);
}

// ---- GEMM step: A (64 x K) staged in K=128 chunks through 4 LDS buffers,
// prefetch depth 2-3, synced by raw vmcnt(N)+s_barrier (never full drain).
// vmcnt accounting audited R7->R8: extra vmem ops (arrive's atomic, wave-0
// flag-spin loads) precede staging in FIFO order or force vmcnt(0), so they
// only over-drain, never under-wait. f2 (optional): flag gating the A2 half,
// polled before chunk 4 is staged — overlaps sibling wait with A1 streaming. ----
template<int ITERS>
__device__ __forceinline__ void gemm_step(
    const __hip_bfloat16* __restrict__ A1,
    const __hip_bfloat16* __restrict__ A2, int* f2,
    const bf16x8* __restrict__ Breg,
    int m0, char* __restrict__ smem, int lane, f32x4* __restrict__ acc) {
  const int tid = threadIdx.x;
  const int s = lane & 15, q = lane >> 4;
#pragma unroll
  for (int mi = 0; mi < 4; ++mi) acc[mi] = (f32x4){0.f, 0.f, 0.f, 0.f};

  auto stage = [&](int c) {
    const __hip_bfloat16* As = (ITERS == 4 || c < 4) ? A1 : A2;
    const int kloc = (c & 3) << 7;
    char* dst = smem + (size_t)((c & 3) << 14);
#pragma unroll
    for (int i = 0; i < 4; ++i) {
      const int u = (i << 8) + tid;          // 0..1023 ; unit = octet*64 + row
      const int o = u >> 6, r = u & 63;
      gl_lds16(dst + (size_t)u * 16, As + (size_t)(m0 + r) * 512 + kloc + (o << 3));
    }
  };
  stage(0); stage(1); stage(2);
#pragma unroll
  for (int it = 0; it < ITERS; ++it) {
    // wait for chunk `it` only; chunks it+1,it+2 stay in flight across barrier
    const int ahead = (ITERS - 1 - it) > 2 ? 2 : (ITERS - 1 - it);
    if (ahead == 2)      asm volatile("s_waitcnt vmcnt(8)\ns_barrier" ::: "memory");
    else if (ahead == 1) asm volatile("s_waitcnt vmcnt(4)\ns_barrier" ::: "memory");
    else                 asm volatile("s_waitcnt vmcnt(0)\ns_barrier" ::: "memory");
    if (ITERS == 8 && it == 1 && f2) waitflag_nb(f2);   // A2 gate before chunk 4
    if (it + 3 < ITERS) stage(it + 3);   // safe: all waves done reading buf (it-1)&3
    const char* sA = smem + (size_t)((it & 3) << 14);
#pragma unroll
    for (int kl = 0; kl < 4; ++kl) {
#pragma unroll
      for (int mi = 0; mi < 4; ++mi) {
        bf16x8 a = *(const bf16x8*)(sA +
            (size_t)((((kl << 2) + q) << 6) + (mi << 4) + s) * 16);
        acc[mi] = __builtin_amdgcn_mfma_f32_16x16x32_bf16(
            a, Breg[(it << 2) + kl], acc[mi], 0, 0, 0);
      }
    }
  }
}

// ---- fused LSTM epilogue: per-wave gate transpose (tbuf), cell math with
// register-resident c, then 4-col regather (hsh) -> one 8B system store/row.
// R6/R7 BUG FIXED HERE: the packed read-back of hsh must NOT be a
// (unsigned long long*) cast over the ushort stores — TBAA treats them as
// non-aliasing and hoists the read above the stores (deterministic garbage).
// __builtin_memcpy is char-typed: always aliases, always ordered. ----
__device__ __forceinline__ void epilogue(
    const f32x4* __restrict__ acc, float* __restrict__ tbuf, ushort* __restrict__ hsh,
    const f32x4 bz, const f32x4* w01, const f32x4* w23, const float2* xr,
    float* __restrict__ creg, __hip_bfloat16* __restrict__ hout,
    int m0, int colbase, int lane) {
  const int s = lane & 15, q = lane >> 4;
  const int row_e = lane >> 2, jl = lane & 3;
#pragma unroll
  for (int mi = 0; mi < 4; ++mi) {
#pragma unroll
    for (int r = 0; r < 4; ++r)
      tbuf[mi * 320 + (q * 4 + r) * 20 + s] = acc[mi][r];
  }
#pragma unroll
  for (int mi = 0; mi < 4; ++mi) {
    f32x4 gv = *(const f32x4*)&tbuf[mi * 320 + row_e * 20 + jl * 4];
    float gi = gv[0] + bz[0], gf = gv[1] + bz[1];
    float gg = gv[2] + bz[2], go = gv[3] + bz[3];
    if (xr) {
      gi += xr[mi].x * (*w01)[0] + xr[mi].y * (*w01)[1];
      gf += xr[mi].x * (*w01)[2] + xr[mi].y * (*w01)[3];
      gg += xr[mi].x * (*w23)[0] + xr[mi].y * (*w23)[1];
      go += xr[mi].x * (*w23)[2] + xr[mi].y * (*w23)[3];
    }
    float iv = sigm(gi), fv = sigm(gf), gvv = tanhf(gg), ov = sigm(go);
    float cv = fv * creg[mi] + iv * gvv;
    creg[mi] = cv;
    __hip_bfloat16 hv = __float2bfloat16(ov * tanhf(cv));
    hsh[(mi << 6) + lane] = __builtin_bit_cast(unsigned short, hv);  // (mi*16+row_e)*4+jl
  }
  // wave-internal regather: lane l owns row m0+l, 4 contiguous cols -> 8B store
  unsigned long long pk;
  asm volatile("" ::: "memory");                    // belt-and-braces ordering
  __builtin_memcpy(&pk, &hsh[lane << 2], 8);        // aliasing-safe packed read
  __hip_atomic_store((unsigned long long*)&hout[(size_t)(m0 + lane) * 512 + colbase],
                     pk, __ATOMIC_RELAXED, __HIP_MEMORY_SCOPE_SYSTEM);
}

// pred spread over all 32 sibling blocks: 2 batch rows each (no straggler)
__device__ __forceinline__ void pred_job2(const __hip_bfloat16* h2, const float* fcW,
                                          const float* fcb, float* outp,
                                          int d2, int g, int nt) {
  const int wv = threadIdx.x >> 6, lane = threadIdx.x & 63;
  if (wv < 2) {
    int b = g * 64 + nt * 2 + wv;
    float s0 = 0.f, s1 = 0.f;
    for (int k = lane; k < 512; k += 64) {
      float hv = __bfloat162float(h2[(size_t)b * 512 + k]);
      s0 += hv * fcW[k];
      s1 += hv * fcW[512 + k];
    }
    for (int off = 32; off; off >>= 1) {
      s0 += __shfl_down(s0, off);
      s1 += __shfl_down(s1, off);
    }
    if (lane == 0) {
      outp[(size_t)b * (HOR * 2) + d2 * 2]     = s0 + fcb[0];
      outp[(size_t)b * (HOR * 2) + d2 * 2 + 1] = s1 + fcb[1];
    }
  }
}

// Persistent kernel: 512 blocks, 2/CU by construction (LDS 64 KB, VGPR capped).
// g = blk&7 pins a batch group's blocks to one XCD under round-robin (perf
// heuristic only; coherence protocol is XCD-agnostic).
__global__ __launch_bounds__(256, 2) void seq2seq_persistent(PK p) {
  __shared__ __align__(16) char smem[65536];   // 4x16KB staging; tbuf/hsh alias
  const int blk = blockIdx.x;
  const int g = blk & 7;
  const int role = (blk >> 3) & 1;
  const int nt = blk >> 4;                     // 0..31 gate-col tile
  const int m0 = g * 64;
  const int wv = threadIdx.x >> 6, lane = threadIdx.x & 63;
  const int s16 = lane & 15, q = lane >> 4;
  const int nrow = nt * 64 + wv * 16 + s16;    // B-frag gate-col row
  const int jl = lane & 3;
  const int jg = nt * 16 + wv * 4 + jl;        // h column this lane owns
  const int n4 = jg * 4;
  const int colbase = nt * 16 + wv * 4;
  float* tbuf = (float*)(smem) + wv * 1280;            // per-wave 5 KB
  ushort* hsh = (ushort*)(smem + 20480) + wv * 256;    // per-wave 512 B

  f32x4 acc[4];
  bf16x8 Breg[32];                             // 128 regs of weights
  float creg[4] = {0.f, 0.f, 0.f, 0.f};        // cell state, register-resident

  if (role == 1) {
    // ---- role B: encoder layer1 (K=1024: [h0[u]; h1[u-1]]), decoder cell2 ----
    load_w<32>(Breg, p.W1c, 1024, nrow, q);
    f32x4 bz = *(const f32x4*)&p.b1r[n4];
    for (int u = 0; u < TT; ++u) {
      waitflag_nb(FL(p.f0, u, g));
      const __hip_bfloat16* A2 = (u == 0) ? p.zbuf : p.h1buf + (size_t)(u - 1) * SLOT;
      int* f2 = (u == 0) ? nullptr : FL(p.f1, u - 1, g);
      gemm_step<8>(p.h0buf + (size_t)u * SLOT, A2, f2, Breg, m0, smem, lane, acc);
      epilogue(acc, tbuf, hsh, bz, nullptr, nullptr, nullptr, creg,
               p.h1buf + (size_t)u * SLOT, m0, colbase, lane);
      arrive(FL(p.f1, u, g));
    }
    load_w<32>(Breg, p.Wd1c, 1024, nrow, q);
    bz = *(const f32x4*)&p.bd1r[n4];
    for (int d = 0; d < HOR; ++d) {
      waitflag_nb(FL(p.fd1, d, g));
      const __hip_bfloat16* A2 = (d == 0) ? p.h1buf + (size_t)127 * SLOT
                                          : p.dh2buf + (size_t)(d - 1) * SLOT;
      int* f2 = (d == 0) ? FL(p.f1, 127, g) : FL(p.fd2, d - 1, g);
      gemm_step<8>(p.dh1buf + (size_t)d * SLOT, A2, f2, Breg, m0, smem, lane, acc);
      epilogue(acc, tbuf, hsh, bz, nullptr, nullptr, nullptr, creg,
               p.dh2buf + (size_t)d * SLOT, m0, colbase, lane);
      arrive(FL(p.fd2, d, g));
    }
  } else {
    // ---- role A: encoder layer0 (K=512), decoder cell1 (K=1024, pred folded) ----
    load_w<16>(Breg, p.W0r, 512, nrow, q);
    f32x4 bz = *(const f32x4*)&p.b0r[n4];
    f32x4 w01 = *(const f32x4*)&p.Wx0r[n4 * 2];
    f32x4 w23 = *(const f32x4*)&p.Wx0r[n4 * 2 + 4];
    const int row_e = lane >> 2;
    for (int s = 0; s < TT; ++s) {
      if (s >= 1) waitflag_nb(FL(p.f0, s - 1, g));
      gemm_step<4>((s == 0) ? p.zbuf : p.h0buf + (size_t)(s - 1) * SLOT, nullptr,
                   nullptr, Breg, m0, smem, lane, acc);
      float2 xr[4];
#pragma unroll
      for (int mi = 0; mi < 4; ++mi)
        xr[mi] = *(const float2*)&p.x[((size_t)(m0 + mi * 16 + row_e) * TT + s) * 2];
      epilogue(acc, tbuf, hsh, bz, &w01, &w23, xr, creg,
               p.h0buf + (size_t)s * SLOT, m0, colbase, lane);
      arrive(FL(p.f0, s, g));
    }
    load_w<32>(Breg, p.Wd0c, 1024, nrow, q);
    f32x4 bzd0 = *(const f32x4*)&p.bd0s0[n4];
    f32x4 bzd  = *(const f32x4*)&p.bd0r[n4];
    for (int d = 0; d < HOR; ++d) {
      const __hip_bfloat16 *A1, *A2; int* f2; f32x4 bzu;
      if (d == 0) {
        waitflag_nb(FL(p.f0, 127, g));
        A1 = p.h0buf + (size_t)127 * SLOT; A2 = p.zbuf; f2 = nullptr; bzu = bzd0;
      } else {
        waitflag_nb(FL(p.fd1, d - 1, g));
        A1 = p.dh1buf + (size_t)(d - 1) * SLOT;
        A2 = p.dh2buf + (size_t)(d - 1) * SLOT;
        f2 = FL(p.fd2, d - 1, g); bzu = bzd;
      }
      gemm_step<8>(A1, A2, f2, Breg, m0, smem, lane, acc);
      epilogue(acc, tbuf, hsh, bzu, nullptr, nullptr, nullptr, creg,
               p.dh1buf + (size_t)d * SLOT, m0, colbase, lane);
      arrive(FL(p.fd1, d, g));
      if (d >= 1)
        pred_job2(p.dh2buf + (size_t)(d - 1) * SLOT, p.fcW, p.fcb, p.out, d - 1, g, nt);
    }
    waitflag_nb(FL(p.fd2, 23, g));
    pred_job2(p.dh2buf + (size_t)23 * SLOT, p.fcW, p.fcb, p.out, 23, g, nt);
  }
}

// Build gate-interleaved bf16 weights, combined biases, and the pred-fold:
// Wd0c[:,512:1024] = dWih0 @ fcW  (rank-2 fold of decoder feedback)
__global__ void prep_weights(
    const float* eWih0, const float* eWhh0, const float* ebih0, const float* ebhh0,
    const float* eWih1, const float* eWhh1, const float* ebih1, const float* ebhh1,
    const float* dWih0, const float* dWhh0, const float* dbih0, const float* dbhh0,
    const float* dWih1, const float* dWhh1, const float* dbih1, const float* dbhh1,
    const float* fcW, const float* fcb,
    __hip_bfloat16* W0r, __hip_bfloat16* W1c, __hip_bfloat16* Wd0c, __hip_bfloat16* Wd1c,
    float* b0r, float* b1r, float* bd0s0, float* bd0r, float* bd1r, float* Wx0r) {
  long idx = (long)blockIdx.x * blockDim.x + threadIdx.x;
  if (idx >= (long)G4 * 3584) return;
  int np = (int)(idx / 3584), kk = (int)(idx % 3584);
  int g = np & 3, j = np >> 2;
  int srow = g * HID + j;
  if (kk < 512) {
    W0r[(size_t)np * 512 + kk] = __float2bfloat16(eWhh0[(size_t)srow * 512 + kk]);
  } else if (kk < 1536) {
    int k2 = kk - 512;
    float v = (k2 < 512) ? eWih1[(size_t)srow * 512 + k2] : eWhh1[(size_t)srow * 512 + (k2 - 512)];
    W1c[(size_t)np * 1024 + k2] = __float2bfloat16(v);
  } else if (kk < 2560) {
    int k2 = kk - 1536;
    float v;
    if (k2 < 512) v = dWhh0[(size_t)srow * 512 + k2];
    else {
      int k3 = k2 - 512;
      v = dWih0[srow * 2] * fcW[k3] + dWih0[srow * 2 + 1] * fcW[512 + k3];
    }
    Wd0c[(size_t)np * 1024 + k2] = __float2bfloat16(v);
  } else {
    int k2 = kk - 2560;
    float v = (k2 < 512) ? dWih1[(size_t)srow * 512 + k2] : dWhh1[(size_t)srow * 512 + (k2 - 512)];
    Wd1c[(size_t)np * 1024 + k2] = __float2bfloat16(v);
  }
  if (kk == 0) {
    b0r[np] = ebih0[srow] + ebhh0[srow];
    b1r[np] = ebih1[srow] + ebhh1[srow];
    float bs0 = dbih0[srow] + dbhh0[srow];
    bd0s0[np] = bs0;
    bd0r[np] = bs0 + dWih0[srow * 2] * fcb[0] + dWih0[srow * 2 + 1] * fcb[1];
    bd1r[np] = dbih1[srow] + dbhh1[srow];
    Wx0r[np * 2]     = eWih0[srow * 2];
    Wx0r[np * 2 + 1] = eWih0[srow * 2 + 1];
  }
}

extern "C" void kernel_launch(void* const* d_in, const int* in_sizes, int n_in,
                              void* d_out, int out_size, void* d_ws, size_t ws_size,
                              hipStream_t stream) {
  (void)in_sizes; (void)n_in; (void)out_size; (void)ws_size;
  const float* x     = (const float*)d_in[0];
  const float* eWih0 = (const float*)d_in[1];
  const float* eWhh0 = (const float*)d_in[2];
  const float* ebih0 = (const float*)d_in[3];
  const float* ebhh0 = (const float*)d_in[4];
  const float* eWih1 = (const float*)d_in[5];
  const float* eWhh1 = (const float*)d_in[6];
  const float* ebih1 = (const float*)d_in[7];
  const float* ebhh1 = (const float*)d_in[8];
  const float* dWih0 = (const float*)d_in[9];
  const float* dWhh0 = (const float*)d_in[10];
  const float* dbih0 = (const float*)d_in[11];
  const float* dbhh0 = (const float*)d_in[12];
  const float* dWih1 = (const float*)d_in[13];
  const float* dWhh1 = (const float*)d_in[14];
  const float* dbih1 = (const float*)d_in[15];
  const float* dbhh1 = (const float*)d_in[16];
  const float* fcW   = (const float*)d_in[17];
  const float* fcb   = (const float*)d_in[18];

  char* ws = (char*)d_ws;
  size_t off = 0;
  auto alloc = [&](size_t bytes) -> char* {
    char* pp = ws + off;
    off = (off + bytes + 255) & ~(size_t)255;
    return pp;
  };

  __hip_bfloat16* W0r  = (__hip_bfloat16*)alloc((size_t)G4 * 512 * 2);
  __hip_bfloat16* W1c  = (__hip_bfloat16*)alloc((size_t)G4 * 1024 * 2);
  __hip_bfloat16* Wd0c = (__hip_bfloat16*)alloc((size_t)G4 * 1024 * 2);
  __hip_bfloat16* Wd1c = (__hip_bfloat16*)alloc((size_t)G4 * 1024 * 2);
  float* b0r   = (float*)alloc(G4 * 4);
  float* b1r   = (float*)alloc(G4 * 4);
  float* bd0s0 = (float*)alloc(G4 * 4);
  float* bd0r  = (float*)alloc(G4 * 4);
  float* bd1r  = (float*)alloc(G4 * 4);
  float* Wx0r  = (float*)alloc(G4 * 2 * 4);

  __hip_bfloat16* h0buf  = (__hip_bfloat16*)alloc((size_t)TT * SLOT * 2);
  __hip_bfloat16* h1buf  = (__hip_bfloat16*)alloc((size_t)TT * SLOT * 2);
  __hip_bfloat16* dh1buf = (__hip_bfloat16*)alloc((size_t)HOR * SLOT * 2);
  __hip_bfloat16* dh2buf = (__hip_bfloat16*)alloc((size_t)HOR * SLOT * 2);

  char* zbase = ws + off;
  __hip_bfloat16* zbuf = (__hip_bfloat16*)alloc((size_t)SLOT * 2);
  int* f0  = (int*)alloc(TT * 8 * 16 * 4);
  int* f1  = (int*)alloc(TT * 8 * 16 * 4);
  int* fd1 = (int*)alloc(HOR * 8 * 16 * 4);
  int* fd2 = (int*)alloc(HOR * 8 * 16 * 4);
  size_t zbytes = (size_t)((ws + off) - zbase);

  hipMemsetAsync(zbase, 0, zbytes, stream);
  prep_weights<<<(int)(((long)G4 * 3584 + 255) / 256), 256, 0, stream>>>(
      eWih0, eWhh0, ebih0, ebhh0, eWih1, eWhh1, ebih1, ebhh1,
      dWih0, dWhh0, dbih0, dbhh0, dWih1, dWhh1, dbih1, dbhh1,
      fcW, fcb, W0r, W1c, Wd0c, Wd1c, b0r, b1r, bd0s0, bd0r, bd1r, Wx0r);

  PK p;
  p.x = x;
  p.W0r = W0r; p.W1c = W1c; p.Wd0c = Wd0c; p.Wd1c = Wd1c;
  p.b0r = b0r; p.b1r = b1r; p.bd0s0 = bd0s0; p.bd0r = bd0r; p.bd1r = bd1r; p.Wx0r = Wx0r;
  p.fcW = fcW; p.fcb = fcb;
  p.h0buf = h0buf; p.h1buf = h1buf; p.dh1buf = dh1buf; p.dh2buf = dh2buf;
  p.zbuf = zbuf;
  p.f0 = f0; p.f1 = f1; p.fd1 = fd1; p.fd2 = fd2;
  p.out = (float*)d_out;

  seq2seq_persistent<<<512, 256, 0, stream>>>(p);
}